// Round 3
// baseline (857.429 us; speedup 1.0000x reference)
//
#include <hip/hip_runtime.h>

// Adaptive separable conv: out[b,c,y,x] = sum_i sum_j inp[b,c,y+i,x+j]*v[b,i,y,x]*h[b,j,y,x]
// B=2,C=3,H=W=256,K=51, fp32. No MFMA (per-pixel weights; no fp32 MFMA on CDNA4).
//
// R3: row-streaming ring buffer to break the LDS occupancy cap.
//  - Tile 16x16, 256-thread blocks (4 waves), grid 16x16x2 = 512 blocks.
//  - Strided i-split: at step t (7 steps), wave s handles taps i = 8t+2s+{0,1}.
//    Block's live rows at step t: [8t, 8t+24) -> 32-row ring per channel.
//  - LDS = 3ch x 32 rows x 80 floats = 30,720 B -> up to 5 blocks/CU.
//    Row stride 80 (80%32==16): adjacent-ty b128 reads hit disjoint bank halves.
//  - Per thread: R=4 x-adjacent outputs x 3 channels; rolling 8-float window per (c,ib),
//    1 ds_read_b128 per 4 j-taps per window (16 FMAs/read); coeff v*h shared over channels.
//  - __launch_bounds__(256,4): VGPR cap 128, demand ~105 -> no spill (R2's failure mode).
//  - Masked tail: taps 51..55 have v4=0; LDS cols 66-67 and rows 66-71 staged from
//    clamped global addrs (finite garbage; only ever multiplied by zero coeffs).

namespace {
constexpr int KK = 51;
constexpr int NB = 2;
constexpr int NC = 3;
constexpr int HH = 256;
constexpr int WW = 256;
constexpr int IN_H = HH + KK - 1;   // 306
constexpr int IN_W = WW + KK - 1;   // 306

constexpr int TW = 16;              // output cols per block
constexpr int TH = 16;              // output rows per block
constexpr int R = 4;                // outputs per thread along x
constexpr int NTX = 4;              // TW / R
constexpr int NTY = 16;             // = TH ; 64 px-threads = 1 wave footprint
constexpr int NS = 4;               // waves (strided i-split)
constexpr int NTHREADS = 256;
constexpr int BI = 2;               // i-taps per wave per step
constexpr int NSTEP = 7;            // ceil(51 / (NS*BI)) ; covers i in [0,56), 51..55 masked
constexpr int RING = 32;            // ring rows per channel (power of 2)
constexpr int LDSW = 80;            // row stride in floats (68 used; %32==16)
constexpr int STAGE_COLS2 = 34;     // float2 per staged row (68 cols incl. 2 masked-tail)
constexpr int KST = HH * WW;        // per-tap plane stride in v/h
}

__device__ __forceinline__ float fget(const float4 v, int i) {
  return (i == 0) ? v.x : (i == 1) ? v.y : (i == 2) ? v.z : v.w;
}

__global__ __launch_bounds__(NTHREADS, 4) void sepconv_kernel(
    const float* __restrict__ inp,
    const float* __restrict__ vert,
    const float* __restrict__ horiz,
    float* __restrict__ out)
{
  __shared__ float ring[NC * RING * LDSW];   // 30,720 B

  const int tid = threadIdx.x;
  const int tx  = tid & (NTX - 1);
  const int ty  = (tid >> 2) & (NTY - 1);
  const int s   = tid >> 6;                  // wave id 0..3 (wave-uniform)

  const int x0 = blockIdx.x * TW;
  const int y0 = blockIdx.y * TH;
  const int bz = blockIdx.z;

  const float* src = inp + (size_t)(bz * NC) * IN_H * IN_W;

  // ---- Init staging: rows [0, 24), 3ch x 34 float2 per row.
  for (int e = tid; e < 24 * NC * STAGE_COLS2; e += NTHREADS) {
    const int col2 = e % STAGE_COLS2;
    const int rc   = e / STAGE_COLS2;
    const int r    = rc % 24;
    const int c    = rc / 24;
    const int gr   = min(y0 + r, IN_H - 1);
    const int gc   = min(x0 + col2 * 2, IN_W - 2);
    const float2 v = *reinterpret_cast<const float2*>(src + ((size_t)c * IN_H + gr) * IN_W + gc);
    float* dst = &ring[(c * RING + (r & (RING - 1))) * LDSW + col2 * 2];
    dst[0] = v.x; dst[1] = v.y;
  }
  __syncthreads();

  const int lx = tx * R;
  const int yg = y0 + ty;
  const int xg = x0 + lx;

  const float* vbase = vert  + (((size_t)bz * KK) * HH + yg) * WW + xg;
  const float* hbase = horiz + (((size_t)bz * KK) * HH + yg) * WW + xg;

  float acc[R][NC];
#pragma unroll
  for (int rx = 0; rx < R; ++rx)
#pragma unroll
    for (int c = 0; c < NC; ++c) acc[rx][c] = 0.0f;

#pragma unroll 1
  for (int t = 0; t < NSTEP; ++t) {
    const int i0 = 8 * t + 2 * s;            // wave's first tap this step

    // Vertical weights for the BI taps (wave-uniform branch; tail -> 0).
    float4 v4[BI];
#pragma unroll
    for (int ib = 0; ib < BI; ++ib) {
      const int i = i0 + ib;
      v4[ib] = (i <= KK - 1)
                 ? *reinterpret_cast<const float4*>(vbase + (size_t)i * KST)
                 : make_float4(0.f, 0.f, 0.f, 0.f);
    }

    // Window row bases in the ring + init windows (cols [lx, lx+8)).
    int   rb[NC][BI];
    float w[NC][BI][8];
#pragma unroll
    for (int c = 0; c < NC; ++c) {
#pragma unroll
      for (int ib = 0; ib < BI; ++ib) {
        const int rr   = ty + i0 + ib;               // <= 15 + 55 = 70 (staged thru 71)
        const int slot = rr & (RING - 1);
        rb[c][ib] = (c * RING + slot) * LDSW + lx;
        const float4* p = reinterpret_cast<const float4*>(&ring[rb[c][ib]]);
        const float4 a = p[0], b = p[1];
        w[c][ib][0] = a.x; w[c][ib][1] = a.y; w[c][ib][2] = a.z; w[c][ib][3] = a.w;
        w[c][ib][4] = b.x; w[c][ib][5] = b.y; w[c][ib][6] = b.z; w[c][ib][7] = b.w;
      }
    }

#pragma unroll
    for (int j0 = 0; j0 < 52; j0 += 4) {     // 13 chunks, fully unrolled
      // Horizontal weights for this chunk (tail j=51 folds to zero at compile time).
      float4 hc[4];
#pragma unroll
      for (int jj = 0; jj < 4; ++jj) {
        const int j = j0 + jj;
        if (j <= KK - 1) {
          hc[jj] = *reinterpret_cast<const float4*>(hbase + (size_t)j * KST);
        } else {
          hc[jj] = make_float4(0.f, 0.f, 0.f, 0.f);
        }
      }

      // coeff = v*h shared across the 3 channels: 32 muls + 96 FMAs per chunk
#pragma unroll
      for (int rx = 0; rx < R; ++rx) {
#pragma unroll
        for (int ib = 0; ib < BI; ++ib) {
          const float vv = fget(v4[ib], rx);
#pragma unroll
          for (int jj = 0; jj < 4; ++jj) {
            const float cf = vv * fget(hc[jj], rx);
#pragma unroll
            for (int c = 0; c < NC; ++c)
              acc[rx][c] = fmaf(cf, w[c][ib][rx + jj], acc[rx][c]);
          }
        }
      }

      // Shift window by 4 (pure renaming under full unroll) and load next quad.
      if (j0 < 48) {
#pragma unroll
        for (int c = 0; c < NC; ++c) {
#pragma unroll
          for (int ib = 0; ib < BI; ++ib) {
#pragma unroll
            for (int q = 0; q < 4; ++q) w[c][ib][q] = w[c][ib][q + 4];
            const float4 n = *reinterpret_cast<const float4*>(&ring[rb[c][ib] + j0 + 8]);
            w[c][ib][4] = n.x; w[c][ib][5] = n.y; w[c][ib][6] = n.z; w[c][ib][7] = n.w;
          }
        }
      }
    }

    // Stage the next 8 rows [8t+24, 8t+32) for step t+1 (slots of dead rows [8t-8,8t)).
    if (t < NSTEP - 1) {
      const int r0 = 8 * t + 24;
      for (int e = tid; e < 8 * NC * STAGE_COLS2; e += NTHREADS) {   // 816 tasks
        const int col2 = e % STAGE_COLS2;
        const int rc   = e / STAGE_COLS2;
        const int r    = r0 + (rc & 7);
        const int c    = rc >> 3;
        const int gr   = min(y0 + r, IN_H - 1);
        const int gc   = min(x0 + col2 * 2, IN_W - 2);
        const float2 v = *reinterpret_cast<const float2*>(src + ((size_t)c * IN_H + gr) * IN_W + gc);
        float* dst = &ring[(c * RING + (r & (RING - 1))) * LDSW + col2 * 2];
        dst[0] = v.x; dst[1] = v.y;
      }
    }
    __syncthreads();
  }

  // ---- Reduce the 4 i-split partials (waves 1..3 -> LDS, wave 0 adds & stores).
  const int lane = tid & 63;
  if (s > 0) {
    float* p = &ring[((s - 1) * 64 + lane) * 12];
#pragma unroll
    for (int rx = 0; rx < R; ++rx)
#pragma unroll
      for (int c = 0; c < NC; ++c) p[rx * NC + c] = acc[rx][c];
  }
  __syncthreads();
  if (s == 0) {
#pragma unroll
    for (int g = 0; g < NS - 1; ++g) {
      const float* p = &ring[(g * 64 + lane) * 12];
#pragma unroll
      for (int rx = 0; rx < R; ++rx)
#pragma unroll
        for (int c = 0; c < NC; ++c) acc[rx][c] += p[rx * NC + c];
    }
#pragma unroll
    for (int c = 0; c < NC; ++c) {
      const float4 o = make_float4(acc[0][c], acc[1][c], acc[2][c], acc[3][c]);
      *reinterpret_cast<float4*>(out + (((size_t)bz * NC + c) * HH + yg) * WW + xg) = o;
    }
  }
}

extern "C" void kernel_launch(void* const* d_in, const int* in_sizes, int n_in,
                              void* d_out, int out_size, void* d_ws, size_t ws_size,
                              hipStream_t stream) {
  const float* inp   = (const float*)d_in[0];
  const float* vert  = (const float*)d_in[1];
  const float* horiz = (const float*)d_in[2];
  float* out = (float*)d_out;

  dim3 grid(WW / TW, HH / TH, NB);   // 16 x 16 x 2 = 512 blocks
  sepconv_kernel<<<grid, NTHREADS, 0, stream>>>(inp, vert, horiz, out);
}

// Round 4
// 637.396 us; speedup vs baseline: 1.3452x; 1.3452x over previous
//
#include <hip/hip_runtime.h>

// Adaptive separable conv: out[b,c,y,x] = sum_i sum_j inp[b,c,y+i,x+j]*v[b,i,y,x]*h[b,j,y,x]
// B=2,C=3,H=W=256,K=51, fp32. No MFMA (per-pixel weights; no fp32 MFMA on CDNA4).
//
// R4 = R3 structure, launch-bounds fix ONLY.
//  - R2/R3 post-mortem: __launch_bounds__(N, 4) clamps the allocator to 64 VGPR
//    (one occupancy bucket tighter than the 128 the arithmetic gives) -> ~110-reg
//    working set spilled to scratch -> FETCH/WRITE blow up, 4% VALUBusy.
//    R1 data point: arg=1 -> natural allocation (172 for ~170 demand), no spill.
//  - Fix: __launch_bounds__(256, 2) (cap 256). Demand ~110 -> expect ~100-130 VGPR,
//    4 waves/SIMD by VGPR, 4-5 blocks/CU by LDS (30.7 KB).
//
// Structure (unchanged from R3):
//  - Tile 16x16, 256-thread blocks (4 waves), grid 16x16x2 = 512 blocks.
//  - Strided i-split: at step t (7 steps), wave s handles taps i = 8t+2s+{0,1}.
//    Live rows at step t: [8t, 8t+24) -> 32-row ring per channel, 8 rows staged/step.
//  - LDS = 3ch x 32 rows x 80 floats = 30,720 B. Row stride 80 (%32==16).
//  - Per thread: R=4 x-adjacent outputs x 3 channels; rolling 8-float window per (c,ib),
//    1 ds_read_b128 per 4 j-taps per window; coeff v*h shared across channels.
//  - Masked tail: taps 51..55 have v4=0; ring rows/cols beyond the image staged from
//    clamped addresses (finite garbage, only multiplied by zero coeffs).

namespace {
constexpr int KK = 51;
constexpr int NB = 2;
constexpr int NC = 3;
constexpr int HH = 256;
constexpr int WW = 256;
constexpr int IN_H = HH + KK - 1;   // 306
constexpr int IN_W = WW + KK - 1;   // 306

constexpr int TW = 16;              // output cols per block
constexpr int TH = 16;              // output rows per block
constexpr int R = 4;                // outputs per thread along x
constexpr int NTX = 4;              // TW / R
constexpr int NTY = 16;             // = TH
constexpr int NS = 4;               // waves (strided i-split)
constexpr int NTHREADS = 256;
constexpr int BI = 2;               // i-taps per wave per step
constexpr int NSTEP = 7;            // covers i in [0,56); 51..55 masked
constexpr int RING = 32;            // ring rows per channel (power of 2)
constexpr int LDSW = 80;            // row stride in floats (68 used; %32==16)
constexpr int STAGE_COLS2 = 34;     // float2 per staged row (68 cols)
constexpr int KST = HH * WW;        // per-tap plane stride in v/h
}

__device__ __forceinline__ float fget(const float4 v, int i) {
  return (i == 0) ? v.x : (i == 1) ? v.y : (i == 2) ? v.z : v.w;
}

__global__ __launch_bounds__(NTHREADS, 2) void sepconv_kernel(
    const float* __restrict__ inp,
    const float* __restrict__ vert,
    const float* __restrict__ horiz,
    float* __restrict__ out)
{
  __shared__ float ring[NC * RING * LDSW];   // 30,720 B

  const int tid = threadIdx.x;
  const int tx  = tid & (NTX - 1);
  const int ty  = (tid >> 2) & (NTY - 1);
  const int s   = tid >> 6;                  // wave id 0..3 (wave-uniform)

  const int x0 = blockIdx.x * TW;
  const int y0 = blockIdx.y * TH;
  const int bz = blockIdx.z;

  const float* src = inp + (size_t)(bz * NC) * IN_H * IN_W;

  // ---- Init staging: rows [0, 24), 3ch x 34 float2 per row.
  for (int e = tid; e < 24 * NC * STAGE_COLS2; e += NTHREADS) {
    const int col2 = e % STAGE_COLS2;
    const int rc   = e / STAGE_COLS2;
    const int r    = rc % 24;
    const int c    = rc / 24;
    const int gr   = min(y0 + r, IN_H - 1);
    const int gc   = min(x0 + col2 * 2, IN_W - 2);
    const float2 v = *reinterpret_cast<const float2*>(src + ((size_t)c * IN_H + gr) * IN_W + gc);
    float* dst = &ring[(c * RING + (r & (RING - 1))) * LDSW + col2 * 2];
    dst[0] = v.x; dst[1] = v.y;
  }
  __syncthreads();

  const int lx = tx * R;
  const int yg = y0 + ty;
  const int xg = x0 + lx;

  const float* vbase = vert  + (((size_t)bz * KK) * HH + yg) * WW + xg;
  const float* hbase = horiz + (((size_t)bz * KK) * HH + yg) * WW + xg;

  float acc[R][NC];
#pragma unroll
  for (int rx = 0; rx < R; ++rx)
#pragma unroll
    for (int c = 0; c < NC; ++c) acc[rx][c] = 0.0f;

#pragma unroll 1
  for (int t = 0; t < NSTEP; ++t) {
    const int i0 = 8 * t + 2 * s;            // wave's first tap this step

    // Vertical weights for the BI taps (wave-uniform branch; tail -> 0).
    float4 v4[BI];
#pragma unroll
    for (int ib = 0; ib < BI; ++ib) {
      const int i = i0 + ib;
      v4[ib] = (i <= KK - 1)
                 ? *reinterpret_cast<const float4*>(vbase + (size_t)i * KST)
                 : make_float4(0.f, 0.f, 0.f, 0.f);
    }

    // Window row bases in the ring + init windows (cols [lx, lx+8)).
    int   rb[NC][BI];
    float w[NC][BI][8];
#pragma unroll
    for (int c = 0; c < NC; ++c) {
#pragma unroll
      for (int ib = 0; ib < BI; ++ib) {
        const int rr   = ty + i0 + ib;               // <= 15 + 55 = 70 (staged thru 71)
        const int slot = rr & (RING - 1);
        rb[c][ib] = (c * RING + slot) * LDSW + lx;
        const float4* p = reinterpret_cast<const float4*>(&ring[rb[c][ib]]);
        const float4 a = p[0], b = p[1];
        w[c][ib][0] = a.x; w[c][ib][1] = a.y; w[c][ib][2] = a.z; w[c][ib][3] = a.w;
        w[c][ib][4] = b.x; w[c][ib][5] = b.y; w[c][ib][6] = b.z; w[c][ib][7] = b.w;
      }
    }

#pragma unroll
    for (int j0 = 0; j0 < 52; j0 += 4) {     // 13 chunks, fully unrolled
      // Horizontal weights for this chunk (tail j=51 folds to zero at compile time).
      float4 hc[4];
#pragma unroll
      for (int jj = 0; jj < 4; ++jj) {
        const int j = j0 + jj;
        if (j <= KK - 1) {
          hc[jj] = *reinterpret_cast<const float4*>(hbase + (size_t)j * KST);
        } else {
          hc[jj] = make_float4(0.f, 0.f, 0.f, 0.f);
        }
      }

      // coeff = v*h shared across the 3 channels: 32 muls + 96 FMAs per chunk
#pragma unroll
      for (int rx = 0; rx < R; ++rx) {
#pragma unroll
        for (int ib = 0; ib < BI; ++ib) {
          const float vv = fget(v4[ib], rx);
#pragma unroll
          for (int jj = 0; jj < 4; ++jj) {
            const float cf = vv * fget(hc[jj], rx);
#pragma unroll
            for (int c = 0; c < NC; ++c)
              acc[rx][c] = fmaf(cf, w[c][ib][rx + jj], acc[rx][c]);
          }
        }
      }

      // Shift window by 4 (pure renaming under full unroll) and load next quad.
      if (j0 < 48) {
#pragma unroll
        for (int c = 0; c < NC; ++c) {
#pragma unroll
          for (int ib = 0; ib < BI; ++ib) {
#pragma unroll
            for (int q = 0; q < 4; ++q) w[c][ib][q] = w[c][ib][q + 4];
            const float4 n = *reinterpret_cast<const float4*>(&ring[rb[c][ib] + j0 + 8]);
            w[c][ib][4] = n.x; w[c][ib][5] = n.y; w[c][ib][6] = n.z; w[c][ib][7] = n.w;
          }
        }
      }
    }

    // Stage the next 8 rows [8t+24, 8t+32) for step t+1 (slots of dead rows [8t-8,8t)).
    if (t < NSTEP - 1) {
      const int r0 = 8 * t + 24;
      for (int e = tid; e < 8 * NC * STAGE_COLS2; e += NTHREADS) {   // 816 tasks
        const int col2 = e % STAGE_COLS2;
        const int rc   = e / STAGE_COLS2;
        const int r    = r0 + (rc & 7);
        const int c    = rc >> 3;
        const int gr   = min(y0 + r, IN_H - 1);
        const int gc   = min(x0 + col2 * 2, IN_W - 2);
        const float2 v = *reinterpret_cast<const float2*>(src + ((size_t)c * IN_H + gr) * IN_W + gc);
        float* dst = &ring[(c * RING + (r & (RING - 1))) * LDSW + col2 * 2];
        dst[0] = v.x; dst[1] = v.y;
      }
    }
    __syncthreads();
  }

  // ---- Reduce the 4 i-split partials (waves 1..3 -> LDS, wave 0 adds & stores).
  const int lane = tid & 63;
  if (s > 0) {
    float* p = &ring[((s - 1) * 64 + lane) * 12];
#pragma unroll
    for (int rx = 0; rx < R; ++rx)
#pragma unroll
      for (int c = 0; c < NC; ++c) p[rx * NC + c] = acc[rx][c];
  }
  __syncthreads();
  if (s == 0) {
#pragma unroll
    for (int g = 0; g < NS - 1; ++g) {
      const float* p = &ring[(g * 64 + lane) * 12];
#pragma unroll
      for (int rx = 0; rx < R; ++rx)
#pragma unroll
        for (int c = 0; c < NC; ++c) acc[rx][c] += p[rx * NC + c];
    }
#pragma unroll
    for (int c = 0; c < NC; ++c) {
      const float4 o = make_float4(acc[0][c], acc[1][c], acc[2][c], acc[3][c]);
      *reinterpret_cast<float4*>(out + (((size_t)bz * NC + c) * HH + yg) * WW + xg) = o;
    }
  }
}

extern "C" void kernel_launch(void* const* d_in, const int* in_sizes, int n_in,
                              void* d_out, int out_size, void* d_ws, size_t ws_size,
                              hipStream_t stream) {
  const float* inp   = (const float*)d_in[0];
  const float* vert  = (const float*)d_in[1];
  const float* horiz = (const float*)d_in[2];
  float* out = (float*)d_out;

  dim3 grid(WW / TW, HH / TH, NB);   // 16 x 16 x 2 = 512 blocks
  sepconv_kernel<<<grid, NTHREADS, 0, stream>>>(inp, vert, horiz, out);
}

// Round 5
// 242.974 us; speedup vs baseline: 3.5289x; 2.6233x over previous
//
#include <hip/hip_runtime.h>

// Adaptive separable conv: out[b,c,y,x] = sum_i sum_j inp[b,c,y+i,x+j]*v[b,i,y,x]*h[b,j,y,x]
// B=2,C=3,H=W=256,K=51, fp32. No MFMA (per-pixel weights; no fp32 MFMA on CDNA4).
//
// R5: one channel per block — shrink per-thread state below every allocator bucket.
//  - R2/R3/R4 post-mortem: compiler clamps VGPRs to an occupancy bucket (64/128) and
//    spills a ~150-reg working set (WRITE_SIZE ~1 GB). Only unspilled regime observed:
//    demand well under the bucket. So: cut demand to ~75 regs structurally.
//  - Grid 48 x 16 x 2 (tile_x = bx&15, c = bx>>4): c-blocks of one tile are 16 apart
//    in dispatch -> same XCD (16 % 8 == 0) -> v/h L2 reuse; v+h (53.5 MB) fits L3 anyway.
//  - Per block: 16x16 output tile of ONE channel. 256 thr; wave s handles taps
//    i = 8t+2s+{0,1} at step t (7 steps). 32-row ring, 8 rows staged per step.
//  - LDS = 32 rows x 84 floats = 10,752 B. Stride 84 (not 80!): 84%32=20, period-8 bank
//    rotation -> 16-row b128 pattern is 2 rows/bank-set = conflict-free (m136).
//    R3/R4's stride 80 put rows ty, ty+2 on identical banks -> the 2.08e7 conflicts.
//  - Per thread: R=4 x-adjacent outputs; rolling 8-float window per i-tap (BI=2);
//    1 ds_read_b128 per 4 j-taps per window (16 FMAs/read).
//  - launch_bounds(256,1): natural allocation (R1 precedent: alloc ~= demand, no spill).

namespace {
constexpr int KK = 51;
constexpr int NB = 2;
constexpr int NC = 3;
constexpr int HH = 256;
constexpr int WW = 256;
constexpr int IN_H = HH + KK - 1;   // 306
constexpr int IN_W = WW + KK - 1;   // 306

constexpr int TW = 16;              // output cols per block
constexpr int TH = 16;              // output rows per block
constexpr int R = 4;                // outputs per thread along x
constexpr int NTX = 4;              // TW / R
constexpr int NTY = 16;             // = TH
constexpr int NS = 4;               // waves (strided i-split)
constexpr int NTHREADS = 256;
constexpr int BI = 2;               // i-taps per wave per step
constexpr int NSTEP = 7;            // covers i in [0,56); 51..55 masked
constexpr int RING = 32;            // ring rows (power of 2)
constexpr int LDSW = 84;            // row stride in floats (68 used; bank period 8)
constexpr int STAGE_COLS2 = 34;     // float2 per staged row (68 cols)
constexpr int KST = HH * WW;        // per-tap plane stride in v/h
}

__device__ __forceinline__ float fget(const float4 v, int i) {
  return (i == 0) ? v.x : (i == 1) ? v.y : (i == 2) ? v.z : v.w;
}

__global__ __launch_bounds__(NTHREADS, 1) void sepconv_kernel(
    const float* __restrict__ inp,
    const float* __restrict__ vert,
    const float* __restrict__ horiz,
    float* __restrict__ out)
{
  __shared__ float ring[RING * LDSW];   // 10,752 B

  const int tid = threadIdx.x;
  const int tx  = tid & (NTX - 1);
  const int ty  = (tid >> 2) & (NTY - 1);
  const int s   = tid >> 6;                  // wave id 0..3 (wave-uniform)

  const int x0 = (blockIdx.x & 15) * TW;
  const int c  = blockIdx.x >> 4;            // channel 0..2
  const int y0 = blockIdx.y * TH;
  const int bz = blockIdx.z;

  const float* src = inp + ((size_t)(bz * NC + c) * IN_H) * IN_W;

  // ---- Init staging: rows [0, 24), 34 float2 per row (816 tasks).
  for (int e = tid; e < 24 * STAGE_COLS2; e += NTHREADS) {
    const int col2 = e % STAGE_COLS2;
    const int r    = e / STAGE_COLS2;
    const int gr   = min(y0 + r, IN_H - 1);
    const int gc   = min(x0 + col2 * 2, IN_W - 2);
    const float2 v = *reinterpret_cast<const float2*>(src + (size_t)gr * IN_W + gc);
    float* dst = &ring[(r & (RING - 1)) * LDSW + col2 * 2];
    dst[0] = v.x; dst[1] = v.y;
  }
  __syncthreads();

  const int lx = tx * R;
  const int yg = y0 + ty;
  const int xg = x0 + lx;

  const float* vbase = vert  + (((size_t)bz * KK) * HH + yg) * WW + xg;
  const float* hbase = horiz + (((size_t)bz * KK) * HH + yg) * WW + xg;

  float acc[R];
#pragma unroll
  for (int rx = 0; rx < R; ++rx) acc[rx] = 0.0f;

#pragma unroll 1
  for (int t = 0; t < NSTEP; ++t) {
    const int i0 = 8 * t + 2 * s;            // wave's first tap this step

    // Vertical weights for the BI taps (wave-uniform branch; tail -> 0).
    float4 v4[BI];
#pragma unroll
    for (int ib = 0; ib < BI; ++ib) {
      const int i = i0 + ib;
      v4[ib] = (i <= KK - 1)
                 ? *reinterpret_cast<const float4*>(vbase + (size_t)i * KST)
                 : make_float4(0.f, 0.f, 0.f, 0.f);
    }

    // Window row bases in the ring + init windows (cols [lx, lx+8)).
    int   rb[BI];
    float w[BI][8];
#pragma unroll
    for (int ib = 0; ib < BI; ++ib) {
      const int rr   = ty + i0 + ib;               // <= 15 + 55 = 70 (staged thru 71)
      const int slot = rr & (RING - 1);
      rb[ib] = slot * LDSW + lx;
      const float4* p = reinterpret_cast<const float4*>(&ring[rb[ib]]);
      const float4 a = p[0], b = p[1];
      w[ib][0] = a.x; w[ib][1] = a.y; w[ib][2] = a.z; w[ib][3] = a.w;
      w[ib][4] = b.x; w[ib][5] = b.y; w[ib][6] = b.z; w[ib][7] = b.w;
    }

#pragma unroll
    for (int j0 = 0; j0 < 52; j0 += 4) {     // 13 chunks, fully unrolled
      // Horizontal weights for this chunk (tail j=51 folds to zero at compile time).
      float4 hc[4];
#pragma unroll
      for (int jj = 0; jj < 4; ++jj) {
        const int j = j0 + jj;
        if (j <= KK - 1) {
          hc[jj] = *reinterpret_cast<const float4*>(hbase + (size_t)j * KST);
        } else {
          hc[jj] = make_float4(0.f, 0.f, 0.f, 0.f);
        }
      }

      // 32 muls + 32 FMAs per chunk
#pragma unroll
      for (int rx = 0; rx < R; ++rx) {
#pragma unroll
        for (int ib = 0; ib < BI; ++ib) {
          const float vv = fget(v4[ib], rx);
#pragma unroll
          for (int jj = 0; jj < 4; ++jj) {
            const float cf = vv * fget(hc[jj], rx);
            acc[rx] = fmaf(cf, w[ib][rx + jj], acc[rx]);
          }
        }
      }

      // Shift window by 4 (register renaming under full unroll) and load next quad.
      if (j0 < 48) {
#pragma unroll
        for (int ib = 0; ib < BI; ++ib) {
#pragma unroll
          for (int q = 0; q < 4; ++q) w[ib][q] = w[ib][q + 4];
          const float4 n = *reinterpret_cast<const float4*>(&ring[rb[ib] + j0 + 8]);
          w[ib][4] = n.x; w[ib][5] = n.y; w[ib][6] = n.z; w[ib][7] = n.w;
        }
      }
    }

    // Stage the next 8 rows [8t+24, 8t+32) for step t+1 (272 tasks).
    if (t < NSTEP - 1) {
      const int r0 = 8 * t + 24;
      for (int e = tid; e < 8 * STAGE_COLS2; e += NTHREADS) {
        const int col2 = e % STAGE_COLS2;
        const int r    = r0 + e / STAGE_COLS2;
        const int gr   = min(y0 + r, IN_H - 1);
        const int gc   = min(x0 + col2 * 2, IN_W - 2);
        const float2 v = *reinterpret_cast<const float2*>(src + (size_t)gr * IN_W + gc);
        float* dst = &ring[(r & (RING - 1)) * LDSW + col2 * 2];
        dst[0] = v.x; dst[1] = v.y;
      }
    }
    __syncthreads();
  }

  // ---- Reduce the 4 i-split partials (waves 1..3 -> LDS, wave 0 adds & stores).
  const int lane = tid & 63;
  if (s > 0) {
    float* p = &ring[((s - 1) * 64 + lane) * 4];
#pragma unroll
    for (int rx = 0; rx < R; ++rx) p[rx] = acc[rx];
  }
  __syncthreads();
  if (s == 0) {
#pragma unroll
    for (int g = 0; g < NS - 1; ++g) {
      const float* p = &ring[(g * 64 + lane) * 4];
#pragma unroll
      for (int rx = 0; rx < R; ++rx) acc[rx] += p[rx];
    }
    const float4 o = make_float4(acc[0], acc[1], acc[2], acc[3]);
    *reinterpret_cast<float4*>(out + (((size_t)bz * NC + c) * HH + yg) * WW + xg) = o;
  }
}

extern "C" void kernel_launch(void* const* d_in, const int* in_sizes, int n_in,
                              void* d_out, int out_size, void* d_ws, size_t ws_size,
                              hipStream_t stream) {
  const float* inp   = (const float*)d_in[0];
  const float* vert  = (const float*)d_in[1];
  const float* horiz = (const float*)d_in[2];
  float* out = (float*)d_out;

  dim3 grid(NC * (WW / TW), HH / TH, NB);   // 48 x 16 x 2 = 1536 blocks
  sepconv_kernel<<<grid, NTHREADS, 0, stream>>>(inp, vert, horiz, out);
}

// Round 6
// 205.783 us; speedup vs baseline: 4.1667x; 1.1807x over previous
//
#include <hip/hip_runtime.h>

// Adaptive separable conv: out[b,c,y,x] = sum_i sum_j inp[b,c,y+i,x+j]*v[b,i,y,x]*h[b,j,y,x]
// B=2,C=3,H=W=256,K=51, fp32. No MFMA (per-pixel weights; no fp32 MFMA on CDNA4).
//
// R6 = R5 (per-channel blocks, row ring) + two fixes:
//  (1) Regrouped accumulation: hacc[i] += h_j*w (1 FMA/tap), acc += v_i*hacc once per
//      step. Halves inner-loop VALU vs R5's cf=v*h + FMA.
//  (2) Runtime j-loop (3 iters x 4 chunks) with 4 rotating float4 window buffers whose
//      roles return to identity each iteration -> no shift-movs, and h-load hoisting is
//      structurally bounded to ~1 iteration. R5's fully-unrolled j-loop let the
//      scheduler hoist h-loads until VGPR=188 (2 waves/SIMD, 27% VALUBusy).
//      Demand now ~96 regs -> __launch_bounds__(256,2) (cap 128) is safe.
//
// Layout (unchanged from R5): grid 48x16x2; per block one channel's 16x16 tile;
// wave s handles taps i=8t+2s+{0,1} at step t (7 steps); 32-row ring x 84-float rows
// (10,752 B LDS); 8 rows staged per step; masked tail taps 51..55 have v4=0.

namespace {
constexpr int KK = 51;
constexpr int NB = 2;
constexpr int NC = 3;
constexpr int HH = 256;
constexpr int WW = 256;
constexpr int IN_H = HH + KK - 1;   // 306
constexpr int IN_W = WW + KK - 1;   // 306

constexpr int TW = 16;              // output cols per block
constexpr int TH = 16;              // output rows per block
constexpr int R = 4;                // outputs per thread along x
constexpr int NTX = 4;              // TW / R
constexpr int NTY = 16;             // = TH
constexpr int NS = 4;               // waves (strided i-split)
constexpr int NTHREADS = 256;
constexpr int BI = 2;               // i-taps per wave per step
constexpr int NSTEP = 7;            // covers i in [0,56); 51..55 masked
constexpr int RING = 32;            // ring rows (power of 2)
constexpr int LDSW = 84;            // row stride in floats (68 used)
constexpr int STAGE_COLS2 = 34;     // float2 per staged row (68 cols)
constexpr int KST = HH * WW;        // 65536 floats per tap plane (j0*KST = j0<<16)
}

__device__ __forceinline__ float fget(const float4 v, int i) {
  return (i == 0) ? v.x : (i == 1) ? v.y : (i == 2) ? v.z : v.w;
}

// One 4-j-tap chunk at runtime j0. Window buffers P[ib][A]=cols[j0,j0+4),
// P[ib][B]=cols[j0+4,j0+8) (relative to lx); loads P[ib][L]=cols[j0+8,j0+12).
// 4 h-loads (shared across both i-taps) + 2 ds_read_b128 + 32 FMA.
template<int A, int B, int L>
__device__ __forceinline__ void do_chunk(int j0, const float* __restrict__ hbase,
                                         const float* ring_, const int (&rb)[BI],
                                         float4 (&P)[BI][4], float (&hacc)[BI][R]) {
  const float* hp = hbase + ((size_t)j0 << 16);
  float4 hc[4];
#pragma unroll
  for (int jj = 0; jj < 4; ++jj)
    hc[jj] = *reinterpret_cast<const float4*>(hp + jj * KST);
#pragma unroll
  for (int ib = 0; ib < BI; ++ib)
    P[ib][L] = *reinterpret_cast<const float4*>(&ring_[rb[ib] + j0 + 8]);
#pragma unroll
  for (int ib = 0; ib < BI; ++ib)
#pragma unroll
    for (int jj = 0; jj < 4; ++jj)
#pragma unroll
      for (int rx = 0; rx < R; ++rx) {
        const int off = rx + jj;                      // 0..6, compile-time
        const float wv = (off < 4) ? fget(P[ib][A], off) : fget(P[ib][B], off - 4);
        hacc[ib][rx] = fmaf(fget(hc[jj], rx), wv, hacc[ib][rx]);
      }
}

__global__ __launch_bounds__(NTHREADS, 2) void sepconv_kernel(
    const float* __restrict__ inp,
    const float* __restrict__ vert,
    const float* __restrict__ horiz,
    float* __restrict__ out)
{
  __shared__ float ring[RING * LDSW];   // 10,752 B

  const int tid = threadIdx.x;
  const int tx  = tid & (NTX - 1);
  const int ty  = (tid >> 2) & (NTY - 1);
  const int s   = tid >> 6;                  // wave id 0..3 (wave-uniform)

  const int x0 = (blockIdx.x & 15) * TW;
  const int c  = blockIdx.x >> 4;            // channel 0..2
  const int y0 = blockIdx.y * TH;
  const int bz = blockIdx.z;

  const float* src = inp + ((size_t)(bz * NC + c) * IN_H) * IN_W;

  // ---- Init staging: rows [0, 24), 34 float2 per row.
  for (int e = tid; e < 24 * STAGE_COLS2; e += NTHREADS) {
    const int col2 = e % STAGE_COLS2;
    const int r    = e / STAGE_COLS2;
    const int gr   = min(y0 + r, IN_H - 1);
    const int gc   = min(x0 + col2 * 2, IN_W - 2);
    const float2 v = *reinterpret_cast<const float2*>(src + (size_t)gr * IN_W + gc);
    float* dst = &ring[(r & (RING - 1)) * LDSW + col2 * 2];
    dst[0] = v.x; dst[1] = v.y;
  }
  __syncthreads();

  const int lx = tx * R;
  const int yg = y0 + ty;
  const int xg = x0 + lx;

  const float* vbase = vert  + (((size_t)bz * KK) * HH + yg) * WW + xg;
  const float* hbase = horiz + (((size_t)bz * KK) * HH + yg) * WW + xg;

  float acc[R] = {0.f, 0.f, 0.f, 0.f};

#pragma unroll 1
  for (int t = 0; t < NSTEP; ++t) {
    const int i0 = 8 * t + 2 * s;            // wave's first tap this step

    // Vertical weights (wave-uniform tail mask -> 0).
    float4 v4[BI];
#pragma unroll
    for (int ib = 0; ib < BI; ++ib) {
      const int i = i0 + ib;
      v4[ib] = (i <= KK - 1)
                 ? *reinterpret_cast<const float4*>(vbase + ((size_t)i << 16))
                 : make_float4(0.f, 0.f, 0.f, 0.f);
    }

    // Window row bases + initial two quads (cols [lx, lx+8)).
    int    rb[BI];
    float4 P[BI][4];
#pragma unroll
    for (int ib = 0; ib < BI; ++ib) {
      const int rr = ty + i0 + ib;                 // <= 70; staged through 71
      rb[ib] = (rr & (RING - 1)) * LDSW + lx;
      P[ib][0] = *reinterpret_cast<const float4*>(&ring[rb[ib]]);
      P[ib][1] = *reinterpret_cast<const float4*>(&ring[rb[ib] + 4]);
    }

    float hacc[BI][R] = {};

    // 12 chunks in a runtime loop; buffer roles identical at each iteration start.
#pragma unroll 1
    for (int cb = 0; cb < 3; ++cb) {
      const int jb = cb * 16;
      do_chunk<0, 1, 2>(jb,      hbase, ring, rb, P, hacc);
      do_chunk<1, 2, 3>(jb + 4,  hbase, ring, rb, P, hacc);
      do_chunk<2, 3, 0>(jb + 8,  hbase, ring, rb, P, hacc);
      do_chunk<3, 0, 1>(jb + 12, hbase, ring, rb, P, hacc);
    }

    // Tail chunk: j = 48,49,50 (j=51 dropped). Uses P[0], P[1]; off = rx+jj <= 5.
    {
      const float* hp = hbase + ((size_t)48 << 16);
      float4 hc[3];
#pragma unroll
      for (int jj = 0; jj < 3; ++jj)
        hc[jj] = *reinterpret_cast<const float4*>(hp + jj * KST);
#pragma unroll
      for (int ib = 0; ib < BI; ++ib)
#pragma unroll
        for (int jj = 0; jj < 3; ++jj)
#pragma unroll
          for (int rx = 0; rx < R; ++rx) {
            const int off = rx + jj;
            const float wv = (off < 4) ? fget(P[ib][0], off) : fget(P[ib][1], off - 4);
            hacc[ib][rx] = fmaf(fget(hc[jj], rx), wv, hacc[ib][rx]);
          }
    }

    // Apply vertical weights once per step.
#pragma unroll
    for (int ib = 0; ib < BI; ++ib)
#pragma unroll
      for (int rx = 0; rx < R; ++rx)
        acc[rx] = fmaf(fget(v4[ib], rx), hacc[ib][rx], acc[rx]);

    // Stage rows [8t+24, 8t+32) for step t+1 (slots disjoint from this step's reads).
    if (t < NSTEP - 1) {
      const int r0 = 8 * t + 24;
      for (int e = tid; e < 8 * STAGE_COLS2; e += NTHREADS) {
        const int col2 = e % STAGE_COLS2;
        const int r    = r0 + e / STAGE_COLS2;
        const int gr   = min(y0 + r, IN_H - 1);
        const int gc   = min(x0 + col2 * 2, IN_W - 2);
        const float2 v = *reinterpret_cast<const float2*>(src + (size_t)gr * IN_W + gc);
        float* dst = &ring[(r & (RING - 1)) * LDSW + col2 * 2];
        dst[0] = v.x; dst[1] = v.y;
      }
    }
    __syncthreads();
  }

  // ---- Reduce the 4 i-split partials (waves 1..3 -> LDS, wave 0 adds & stores).
  const int lane = tid & 63;
  if (s > 0) {
    float* p = &ring[((s - 1) * 64 + lane) * 4];
#pragma unroll
    for (int rx = 0; rx < R; ++rx) p[rx] = acc[rx];
  }
  __syncthreads();
  if (s == 0) {
#pragma unroll
    for (int g = 0; g < NS - 1; ++g) {
      const float* p = &ring[(g * 64 + lane) * 4];
#pragma unroll
      for (int rx = 0; rx < R; ++rx) acc[rx] += p[rx];
    }
    const float4 o = make_float4(acc[0], acc[1], acc[2], acc[3]);
    *reinterpret_cast<float4*>(out + (((size_t)bz * NC + c) * HH + yg) * WW + xg) = o;
  }
}

extern "C" void kernel_launch(void* const* d_in, const int* in_sizes, int n_in,
                              void* d_out, int out_size, void* d_ws, size_t ws_size,
                              hipStream_t stream) {
  const float* inp   = (const float*)d_in[0];
  const float* vert  = (const float*)d_in[1];
  const float* horiz = (const float*)d_in[2];
  float* out = (float*)d_out;

  dim3 grid(NC * (WW / TW), HH / TH, NB);   // 48 x 16 x 2 = 1536 blocks
  sepconv_kernel<<<grid, NTHREADS, 0, stream>>>(inp, vert, horiz, out);
}